// Round 3
// baseline (222.308 us; speedup 1.0000x reference)
//
#include <hip/hip_runtime.h>
#include <hip/hip_bf16.h>
#include <math.h>

// B=4, N=4096, F=512, C=64. M = B*N = 16384 rows.
#define M_ROWS 16384
#define F_DIM 512
#define C_DIM 64

typedef short bf16x8 __attribute__((ext_vector_type(8)));
typedef float floatx4 __attribute__((ext_vector_type(4)));
typedef unsigned short ushortx8 __attribute__((ext_vector_type(8)));
typedef unsigned short ushortx4 __attribute__((ext_vector_type(4)));

static __device__ __forceinline__ unsigned short f2bf(float x) {
    __hip_bfloat16 h = __float2bfloat16(x);   // RN
    return *reinterpret_cast<unsigned short*>(&h);
}
static __device__ __forceinline__ float bf2f(unsigned short h) {
    unsigned int u = ((unsigned int)h) << 16;
    return __builtin_bit_cast(float, u);
}

// LDS-only barrier: global loads stay in flight (no vmcnt(0) drain).
static __device__ __forceinline__ void lgkm_barrier() {
    asm volatile("s_waitcnt lgkmcnt(0)\n\ts_barrier" ::: "memory");
}

// ---------------------------------------------------------------------------
// Frag-linear layouts (MFMA B-operand order): element (n,k) of a 16-col group
// lives at lane=(k>>3&3)*16+(n&15), j=k&7 -> [group][lane][8] contiguous.
//   wt    : group = (c>>4)*16 + (k>>5)            (640 cols x 512 k)
//   h_sw  : [b][mtile(64)][group=(Fcol>>4)*2+(mloc>>5)][lane][8]
// ---------------------------------------------------------------------------

// Kernel 0: weight transpose + bf16 hi/lo split -> frag-linear.
__global__ __launch_bounds__(64) void prep_w_kernel(
    const float* __restrict__ Wf, const float* __restrict__ Wg,
    const float* __restrict__ Wh,
    unsigned short* __restrict__ wt_hi, unsigned short* __restrict__ wt_lo)
{
    const int c = blockIdx.x;
    const int t = threadIdx.x;
    const float* W; int ld, cl;
    if (c < 64)       { W = Wf; ld = C_DIM; cl = c; }
    else if (c < 128) { W = Wg; ld = C_DIM; cl = c - 64; }
    else              { W = Wh; ld = F_DIM; cl = c - 128; }
    const int ng = c >> 4, l16 = c & 15;
    for (int k = t; k < F_DIM; k += 64) {
        const float x = W[(size_t)k * ld + cl];
        const unsigned short h = f2bf(x);
        const int kh = k >> 5, qd = (k >> 3) & 3, j = k & 7;
        const size_t off = (((size_t)(ng * 16 + kh) * 64) + qd * 16 + l16) * 8 + j;
        wt_hi[off] = h;
        wt_lo[off] = f2bf(x - bf2f(h));
    }
}

// ---------------------------------------------------------------------------
// Kernel 1: MFMA embed GEMM, 64 rows x 128 cols per block. blockIdx.y:
// 0 -> f|g fused (hi/lo 3-MFMA path), 1..4 -> h cols (y-1)*128 (plain bf16).
// Wave w owns cols w*32..+32. B frags straight from global frag-linear wt.
// ---------------------------------------------------------------------------
#define BM 64
#define LDK 72

__global__ __launch_bounds__(256, 4) void embed_mfma_kernel(
    const float* __restrict__ V,
    const unsigned short* __restrict__ wt_hi, const unsigned short* __restrict__ wt_lo,
    const float* __restrict__ bf, const float* __restrict__ bg,
    const float* __restrict__ bh,
    unsigned short* __restrict__ f_bf, unsigned short* __restrict__ g_bf,
    unsigned short* __restrict__ h_sw)
{
    __shared__ __align__(16) unsigned short a_hi[BM][LDK];
    __shared__ __align__(16) unsigned short a_lo[BM][LDK];

    const int t  = threadIdx.x;
    const int R0 = blockIdx.x * BM;
    const bool fg = (blockIdx.y == 0);
    const int cbase = fg ? 0 : blockIdx.y * 128;   // wt col base (g at 64, h at 128+)

    const int w = t >> 6, lane = t & 63, quad = lane >> 4, l16 = lane & 15;

    floatx4 acc[4][2];
    #pragma unroll
    for (int rt = 0; rt < 4; ++rt)
        #pragma unroll
        for (int c = 0; c < 2; ++c)
            acc[rt][c] = (floatx4){0.f, 0.f, 0.f, 0.f};

    const int arow = t >> 4;          // 0..15 (+16/round)
    const int acol = (t & 15) * 4;    // float index (16 B chunks)
    const int ng0  = (cbase >> 4) + w * 2;

    #pragma unroll 1
    for (int k0 = 0; k0 < F_DIM; k0 += 64) {
        lgkm_barrier();   // protect previous iteration's a-frag reads
        // ---- stage A: V fp32 -> bf16 hi/lo in LDS ----
        #pragma unroll
        for (int rr = 0; rr < 4; ++rr) {
            const int row = rr * 16 + arow;
            const float4 x = *(const float4*)(V + (size_t)(R0 + row) * F_DIM + k0 + acol);
            const float xs[4] = {x.x, x.y, x.z, x.w};
            ushortx4 hi, lo;
            #pragma unroll
            for (int jj = 0; jj < 4; ++jj) {
                const unsigned short hb2 = f2bf(xs[jj]);
                hi[jj] = hb2;
                lo[jj] = f2bf(xs[jj] - bf2f(hb2));
            }
            *(ushortx4*)&a_hi[row][acol] = hi;
            if (fg) *(ushortx4*)&a_lo[row][acol] = lo;
        }
        lgkm_barrier();
        // ---- compute ----
        #pragma unroll
        for (int kk = 0; kk < 2; ++kk) {
            const int kh = (k0 >> 5) + kk;
            const bf16x8 b0 = *(const bf16x8*)(wt_hi + (((size_t)(ng0 * 16 + kh)) * 64 + lane) * 8);
            const bf16x8 b1 = *(const bf16x8*)(wt_hi + (((size_t)((ng0 + 1) * 16 + kh)) * 64 + lane) * 8);
            bf16x8 ah[4];
            #pragma unroll
            for (int rt = 0; rt < 4; ++rt)
                ah[rt] = *(const bf16x8*)&a_hi[rt * 16 + l16][kk * 32 + quad * 8];
            #pragma unroll
            for (int rt = 0; rt < 4; ++rt) {
                acc[rt][0] = __builtin_amdgcn_mfma_f32_16x16x32_bf16(ah[rt], b0, acc[rt][0], 0, 0, 0);
                acc[rt][1] = __builtin_amdgcn_mfma_f32_16x16x32_bf16(ah[rt], b1, acc[rt][1], 0, 0, 0);
            }
            if (fg) {
                const bf16x8 c0 = *(const bf16x8*)(wt_lo + (((size_t)(ng0 * 16 + kh)) * 64 + lane) * 8);
                const bf16x8 c1 = *(const bf16x8*)(wt_lo + (((size_t)((ng0 + 1) * 16 + kh)) * 64 + lane) * 8);
                bf16x8 al[4];
                #pragma unroll
                for (int rt = 0; rt < 4; ++rt)
                    al[rt] = *(const bf16x8*)&a_lo[rt * 16 + l16][kk * 32 + quad * 8];
                #pragma unroll
                for (int rt = 0; rt < 4; ++rt) {
                    acc[rt][0] = __builtin_amdgcn_mfma_f32_16x16x32_bf16(ah[rt], c0, acc[rt][0], 0, 0, 0);
                    acc[rt][0] = __builtin_amdgcn_mfma_f32_16x16x32_bf16(al[rt], b0, acc[rt][0], 0, 0, 0);
                    acc[rt][1] = __builtin_amdgcn_mfma_f32_16x16x32_bf16(ah[rt], c1, acc[rt][1], 0, 0, 0);
                    acc[rt][1] = __builtin_amdgcn_mfma_f32_16x16x32_bf16(al[rt], b1, acc[rt][1], 0, 0, 0);
                }
            }
        }
    }

    // ---- epilogue: bias + relu + bf16, route by wt column ----
    #pragma unroll
    for (int rt = 0; rt < 4; ++rt) {
        #pragma unroll
        for (int c = 0; c < 2; ++c) {
            const int wtc  = cbase + w * 32 + c * 16 + l16;   // 0..639
            const int rowl = rt * 16 + quad * 4;
            const float bias = fg ? (wtc < 64 ? bf[wtc] : bg[wtc - 64]) : bh[wtc - 128];
            const floatx4 v = acc[rt][c];
            if (fg) {
                unsigned short* dst = (wtc < 64) ? (f_bf + wtc) : (g_bf + wtc - 64);
                #pragma unroll
                for (int r = 0; r < 4; ++r) {
                    const float z = v[r] + bias;
                    dst[(size_t)(R0 + rowl + r) * C_DIM] = f2bf(z > 0.f ? z : 0.f);
                }
            } else {
                const int hc   = wtc - 128;                   // global F col
                const int grow = R0 + rowl;
                const int b    = grow >> 12, rl = grow & 4095;
                const int T    = rl >> 6, mloc = rl & 63;
                const int kh2  = mloc >> 5, q2 = (mloc >> 3) & 3, j0 = mloc & 7;
                ushortx4 st;
                #pragma unroll
                for (int r = 0; r < 4; ++r) {
                    const float z = v[r] + bias;
                    st[r] = f2bf(z > 0.f ? z : 0.f);
                }
                const size_t off = ((((size_t)(b * 64 + T) * 64) + (hc >> 4) * 2 + kh2) * 64
                                    + q2 * 16 + (hc & 15)) * 8 + j0;
                *(ushortx4*)(h_sw + off) = st;
            }
        }
    }
}

// ---------------------------------------------------------------------------
// Kernel 2: MFMA attention, fully fused. QT=32 q-rows per block, 512 threads
// (8 waves), grid = 4 batches x 128 q-tiles = 512 blocks -> 2 BLOCKS PER CU.
// Rationale (round-1 post-mortem): at 1 block/CU every barrier idled the
// whole CU (~30% bare stall). With 2 co-resident blocks one block's
// barrier/exp/VMEM-latency stalls are covered by the other's PV MFMAs.
// Per-wave per-iter work unchanged (2 score + 16 PV MFMA); per-CU MFMA
// density unchanged; stalls now overlapped.
//
// LDS tiles: exact 128 B stride, T2 XOR-swizzle (byte ^= (row&7)<<4) ->
// conflict-free ds_read_b128 / staged writes (verified 0 conflicts in r1).
//
// Score partition: wave w -> rows (w&1)*16, cols (w>>1)*16 of the 32x64
// score tile (one 16x16 tile each). PV partition: wave w owns BOTH 16-row
// tiles x 64 F-cols [w*64,+64); its 8 h frags (groups 8w..8w+7) are one
// contiguous 8 KB block, so 8 waves tile the 64 KB h mtile exactly once.
// Barriers lgkm-only. Epilogue: out = gamma*O/l + V in fp32 (final).
// ---------------------------------------------------------------------------
#define QT 32
#define KT 64

__global__ __launch_bounds__(512, 4) void attn_mfma_kernel(
    const unsigned short* __restrict__ f_bf, const unsigned short* __restrict__ g_bf,
    const unsigned short* __restrict__ h_sw, const float* __restrict__ gamma,
    const float* __restrict__ V, float* __restrict__ out)
{
    __shared__ __align__(16) unsigned short p_lds[2][QT * 64];   // 8 KB, swizzled
    __shared__ __align__(16) unsigned short g_lds[2][KT * 64];   // 16 KB, swizzled
    __shared__ float l_red[4][QT];
    __shared__ float l_inv[QT];

    const int t = threadIdx.x;
    const int w = t >> 6, lane = t & 63, quad = lane >> 4, l16 = lane & 15;
    const int wr = w & 1, wc = w >> 1;     // score stripe: rows wr*16, cols wc*16

    // XCD-chunked mapping: XCD x (=bid&7) gets 64 consecutive q-tiles of one
    // batch half -> per-XCD L2 streams exactly one batch's h (4 MB, L2-fit).
    const int bid  = blockIdx.x;
    const int orig = (bid & 7) * 64 + (bid >> 3);
    const int b    = orig >> 7, qb = orig & 127;
    const int R0   = qb * QT;

    const unsigned short* fb    = f_bf + ((size_t)b * 4096 + R0) * C_DIM;
    const unsigned short* gb    = g_bf + (size_t)b * 4096 * C_DIM;
    const unsigned short* hbase = h_sw + (size_t)b * 64 * 32768;

    bf16x8 f0, f1;
    {
        const unsigned short* fr = fb + (size_t)(wr * 16 + l16) * C_DIM + quad * 8;
        f0 = *(const bf16x8*)fr;
        f1 = *(const bf16x8*)(fr + 32);
    }
    float gam[4];
    #pragma unroll
    for (int cg = 0; cg < 4; ++cg)
        gam[cg] = gamma[w * 64 + cg * 16 + l16];

    floatx4 acc[2][4];   // [row-tile][col-16-group]; cols w*64 + cg*16
    #pragma unroll
    for (int rt = 0; rt < 2; ++rt)
        #pragma unroll
        for (int cg = 0; cg < 4; ++cg)
            acc[rt][cg] = (floatx4){0.f, 0.f, 0.f, 0.f};
    float run_l[4] = {0.f, 0.f, 0.f, 0.f};

    // cooperative g stage: thread t -> (row=t>>3, 16 B chunk), swizzled dest
    const int grow    = t >> 3, gck = (t & 7) * 16;          // byte chunk
    const int g_swoff = grow * 128 + (gck ^ ((grow & 7) << 4));
    ushortx8 greg = *(const ushortx8*)(gb + (size_t)grow * C_DIM + (t & 7) * 8);

    // loop-invariant swizzled read offsets
    const int sgrow   = wc * 16 + l16;                       // g row for scores
    const int sg_off0 = sgrow * 128 + ((quad * 16)      ^ ((sgrow & 7) << 4));
    const int sg_off1 = sgrow * 128 + ((quad * 16 + 64) ^ ((sgrow & 7) << 4));

    for (int it = 0; it < 64; ++it) {
        const int buf = it & 1;
        const unsigned short* ht = hbase + (size_t)it * 32768 + (size_t)w * 4096;

        // ---- h prefetch: this wave's contiguous 8 KB (groups 8w..8w+7) ----
        bf16x8 h[8];
        #pragma unroll
        for (int gi = 0; gi < 8; ++gi)
            h[gi] = *(const bf16x8*)(ht + gi * 512 + (size_t)lane * 8);

        *(ushortx8*)((unsigned char*)&g_lds[buf][0] + g_swoff) = greg;
        if (it < 63)
            greg = *(const ushortx8*)(gb + (size_t)((it + 1) * KT + grow) * C_DIM + (t & 7) * 8);
        lgkm_barrier();   // g[buf] visible

        const unsigned char* gB = (const unsigned char*)&g_lds[buf][0];
        unsigned char*       pB = (unsigned char*)&p_lds[buf][0];

        // ---- scores: rows wr*16..+16, cols wc*16..+16 (one tile/wave) ----
        {
            const bf16x8 g0 = *(const bf16x8*)(gB + sg_off0);
            const bf16x8 g1 = *(const bf16x8*)(gB + sg_off1);
            floatx4 cc = (floatx4){0.f, 0.f, 0.f, 0.f};
            cc = __builtin_amdgcn_mfma_f32_16x16x32_bf16(f0, g0, cc, 0, 0, 0);
            cc = __builtin_amdgcn_mfma_f32_16x16x32_bf16(f1, g1, cc, 0, 0, 0);
            #pragma unroll
            for (int r = 0; r < 4; ++r) {
                const float p = __expf(cc[r] - 32.f);
                run_l[r] += p;
                const int prow = wr * 16 + quad * 4 + r;
                const int pcol = wc * 16 + l16;
                *(unsigned short*)(pB + prow * 128 + ((pcol * 2) ^ ((prow & 7) << 4))) = f2bf(p);
            }
        }
        lgkm_barrier();   // p[buf] visible

        // ---- PV: all 32 rows x this wave's 64 cols ----
        #pragma unroll
        for (int rt = 0; rt < 2; ++rt) {
            const int prow = rt * 16 + l16;
            const int sw   = (prow & 7) << 4;
            const bf16x8 pf0 = *(const bf16x8*)(pB + prow * 128 + ((quad * 16)      ^ sw));
            const bf16x8 pf1 = *(const bf16x8*)(pB + prow * 128 + ((quad * 16 + 64) ^ sw));
            #pragma unroll
            for (int cg = 0; cg < 4; ++cg) {
                acc[rt][cg] = __builtin_amdgcn_mfma_f32_16x16x32_bf16(pf0, h[2 * cg],     acc[rt][cg], 0, 0, 0);
                acc[rt][cg] = __builtin_amdgcn_mfma_f32_16x16x32_bf16(pf1, h[2 * cg + 1], acc[rt][cg], 0, 0, 0);
            }
        }
    }

    // ---- full row-sum l: shfl over l16, then LDS-sum across the 4 wc ----
    #pragma unroll
    for (int r = 0; r < 4; ++r) {
        float v = run_l[r];
        v += __shfl_xor(v, 1, 64);
        v += __shfl_xor(v, 2, 64);
        v += __shfl_xor(v, 4, 64);
        v += __shfl_xor(v, 8, 64);
        if (l16 == 0) l_red[wc][wr * 16 + quad * 4 + r] = v;
    }
    __syncthreads();
    if (t < QT)
        l_inv[t] = 1.f / (l_red[0][t] + l_red[1][t] + l_red[2][t] + l_red[3][t]);
    __syncthreads();

    // ---- fused epilogue: out = gamma * O/l + V (fp32, final) ----
    const float* Vb = V   + ((size_t)b * 4096 + R0) * F_DIM;
    float*       ob = out + ((size_t)b * 4096 + R0) * F_DIM;
    #pragma unroll
    for (int rt = 0; rt < 2; ++rt) {
        #pragma unroll
        for (int r = 0; r < 4; ++r) {
            const int row = rt * 16 + quad * 4 + r;
            const float li = l_inv[row];
            #pragma unroll
            for (int cg = 0; cg < 4; ++cg) {
                const int col = w * 64 + cg * 16 + l16;
                ob[(size_t)row * F_DIM + col] =
                    gam[cg] * acc[rt][cg][r] * li + Vb[(size_t)row * F_DIM + col];
            }
        }
    }
}

// ---------------------------------------------------------------------------
extern "C" void kernel_launch(void* const* d_in, const int* in_sizes, int n_in,
                              void* d_out, int out_size, void* d_ws, size_t ws_size,
                              hipStream_t stream) {
    const float* V     = (const float*)d_in[0];
    const float* Wf    = (const float*)d_in[1];
    const float* bf    = (const float*)d_in[2];
    const float* Wg    = (const float*)d_in[3];
    const float* bg    = (const float*)d_in[4];
    const float* Wh    = (const float*)d_in[5];
    const float* bh    = (const float*)d_in[6];
    const float* gamma = (const float*)d_in[7];
    float* out = (float*)d_out;

    // ws: f 2MB | g 2MB | h_sw 16MB | wt_hi 0.64 | wt_lo 0.64
    unsigned short* f_bf  = (unsigned short*)d_ws;
    unsigned short* g_bf  = f_bf + (size_t)M_ROWS * C_DIM;
    unsigned short* h_sw  = g_bf + (size_t)M_ROWS * C_DIM;
    unsigned short* wt_hi = h_sw + (size_t)4 * F_DIM * 4096;
    unsigned short* wt_lo = wt_hi + (size_t)640 * F_DIM;

    prep_w_kernel<<<640, 64, 0, stream>>>(Wf, Wg, Wh, wt_hi, wt_lo);
    embed_mfma_kernel<<<dim3(M_ROWS / BM, 5), 256, 0, stream>>>(
        V, wt_hi, wt_lo, bf, bg, bh, f_bf, g_bf, h_sw);
    attn_mfma_kernel<<<512, 512, 0, stream>>>(f_bf, g_bf, h_sw, gamma, V, out);
}

// Round 4
// 217.294 us; speedup vs baseline: 1.0231x; 1.0231x over previous
//
#include <hip/hip_runtime.h>
#include <hip/hip_bf16.h>
#include <math.h>

// B=4, N=4096, F=512, C=64. M = B*N = 16384 rows.
#define M_ROWS 16384
#define F_DIM 512
#define C_DIM 64

typedef short bf16x8 __attribute__((ext_vector_type(8)));
typedef float floatx4 __attribute__((ext_vector_type(4)));
typedef unsigned short ushortx8 __attribute__((ext_vector_type(8)));
typedef unsigned short ushortx4 __attribute__((ext_vector_type(4)));

static __device__ __forceinline__ unsigned short f2bf(float x) {
    __hip_bfloat16 h = __float2bfloat16(x);   // RN
    return *reinterpret_cast<unsigned short*>(&h);
}
static __device__ __forceinline__ float bf2f(unsigned short h) {
    unsigned int u = ((unsigned int)h) << 16;
    return __builtin_bit_cast(float, u);
}

// LDS-only barrier: global loads stay in flight (no vmcnt(0) drain).
static __device__ __forceinline__ void lgkm_barrier() {
    asm volatile("s_waitcnt lgkmcnt(0)\n\ts_barrier" ::: "memory");
}

// ---------------------------------------------------------------------------
// Frag-linear layouts (MFMA B-operand order): element (n,k) of a 16-col group
// lives at lane=(k>>3&3)*16+(n&15), j=k&7 -> [group][lane][8] contiguous.
//   wt    : group = (c>>4)*16 + (k>>5)            (640 cols x 512 k)
//   h_sw  : [b][mtile(64)][group=(Fcol>>4)*2+(mloc>>5)][lane][8]
// ---------------------------------------------------------------------------

// Kernel 0: weight transpose + bf16 hi/lo split -> frag-linear.
__global__ __launch_bounds__(64) void prep_w_kernel(
    const float* __restrict__ Wf, const float* __restrict__ Wg,
    const float* __restrict__ Wh,
    unsigned short* __restrict__ wt_hi, unsigned short* __restrict__ wt_lo)
{
    const int c = blockIdx.x;
    const int t = threadIdx.x;
    const float* W; int ld, cl;
    if (c < 64)       { W = Wf; ld = C_DIM; cl = c; }
    else if (c < 128) { W = Wg; ld = C_DIM; cl = c - 64; }
    else              { W = Wh; ld = F_DIM; cl = c - 128; }
    const int ng = c >> 4, l16 = c & 15;
    for (int k = t; k < F_DIM; k += 64) {
        const float x = W[(size_t)k * ld + cl];
        const unsigned short h = f2bf(x);
        const int kh = k >> 5, qd = (k >> 3) & 3, j = k & 7;
        const size_t off = (((size_t)(ng * 16 + kh) * 64) + qd * 16 + l16) * 8 + j;
        wt_hi[off] = h;
        wt_lo[off] = f2bf(x - bf2f(h));
    }
}

// ---------------------------------------------------------------------------
// Kernel 1: MFMA embed GEMM, 64 rows x 128 cols per block. blockIdx.y:
// 0 -> f|g fused (hi/lo 3-MFMA path), 1..4 -> h cols (y-1)*128 (plain bf16).
// Wave w owns cols w*32..+32. B frags straight from global frag-linear wt.
// ---------------------------------------------------------------------------
#define BM 64
#define LDK 72

__global__ __launch_bounds__(256, 4) void embed_mfma_kernel(
    const float* __restrict__ V,
    const unsigned short* __restrict__ wt_hi, const unsigned short* __restrict__ wt_lo,
    const float* __restrict__ bf, const float* __restrict__ bg,
    const float* __restrict__ bh,
    unsigned short* __restrict__ f_bf, unsigned short* __restrict__ g_bf,
    unsigned short* __restrict__ h_sw)
{
    __shared__ __align__(16) unsigned short a_hi[BM][LDK];
    __shared__ __align__(16) unsigned short a_lo[BM][LDK];

    const int t  = threadIdx.x;
    const int R0 = blockIdx.x * BM;
    const bool fg = (blockIdx.y == 0);
    const int cbase = fg ? 0 : blockIdx.y * 128;   // wt col base (g at 64, h at 128+)

    const int w = t >> 6, lane = t & 63, quad = lane >> 4, l16 = lane & 15;

    floatx4 acc[4][2];
    #pragma unroll
    for (int rt = 0; rt < 4; ++rt)
        #pragma unroll
        for (int c = 0; c < 2; ++c)
            acc[rt][c] = (floatx4){0.f, 0.f, 0.f, 0.f};

    const int arow = t >> 4;          // 0..15 (+16/round)
    const int acol = (t & 15) * 4;    // float index (16 B chunks)
    const int ng0  = (cbase >> 4) + w * 2;

    #pragma unroll 1
    for (int k0 = 0; k0 < F_DIM; k0 += 64) {
        lgkm_barrier();   // protect previous iteration's a-frag reads
        // ---- stage A: V fp32 -> bf16 hi/lo in LDS ----
        #pragma unroll
        for (int rr = 0; rr < 4; ++rr) {
            const int row = rr * 16 + arow;
            const float4 x = *(const float4*)(V + (size_t)(R0 + row) * F_DIM + k0 + acol);
            const float xs[4] = {x.x, x.y, x.z, x.w};
            ushortx4 hi, lo;
            #pragma unroll
            for (int jj = 0; jj < 4; ++jj) {
                const unsigned short hb2 = f2bf(xs[jj]);
                hi[jj] = hb2;
                lo[jj] = f2bf(xs[jj] - bf2f(hb2));
            }
            *(ushortx4*)&a_hi[row][acol] = hi;
            if (fg) *(ushortx4*)&a_lo[row][acol] = lo;
        }
        lgkm_barrier();
        // ---- compute ----
        #pragma unroll
        for (int kk = 0; kk < 2; ++kk) {
            const int kh = (k0 >> 5) + kk;
            const bf16x8 b0 = *(const bf16x8*)(wt_hi + (((size_t)(ng0 * 16 + kh)) * 64 + lane) * 8);
            const bf16x8 b1 = *(const bf16x8*)(wt_hi + (((size_t)((ng0 + 1) * 16 + kh)) * 64 + lane) * 8);
            bf16x8 ah[4];
            #pragma unroll
            for (int rt = 0; rt < 4; ++rt)
                ah[rt] = *(const bf16x8*)&a_hi[rt * 16 + l16][kk * 32 + quad * 8];
            #pragma unroll
            for (int rt = 0; rt < 4; ++rt) {
                acc[rt][0] = __builtin_amdgcn_mfma_f32_16x16x32_bf16(ah[rt], b0, acc[rt][0], 0, 0, 0);
                acc[rt][1] = __builtin_amdgcn_mfma_f32_16x16x32_bf16(ah[rt], b1, acc[rt][1], 0, 0, 0);
            }
            if (fg) {
                const bf16x8 c0 = *(const bf16x8*)(wt_lo + (((size_t)(ng0 * 16 + kh)) * 64 + lane) * 8);
                const bf16x8 c1 = *(const bf16x8*)(wt_lo + (((size_t)((ng0 + 1) * 16 + kh)) * 64 + lane) * 8);
                bf16x8 al[4];
                #pragma unroll
                for (int rt = 0; rt < 4; ++rt)
                    al[rt] = *(const bf16x8*)&a_lo[rt * 16 + l16][kk * 32 + quad * 8];
                #pragma unroll
                for (int rt = 0; rt < 4; ++rt) {
                    acc[rt][0] = __builtin_amdgcn_mfma_f32_16x16x32_bf16(ah[rt], c0, acc[rt][0], 0, 0, 0);
                    acc[rt][0] = __builtin_amdgcn_mfma_f32_16x16x32_bf16(al[rt], b0, acc[rt][0], 0, 0, 0);
                    acc[rt][1] = __builtin_amdgcn_mfma_f32_16x16x32_bf16(ah[rt], c1, acc[rt][1], 0, 0, 0);
                    acc[rt][1] = __builtin_amdgcn_mfma_f32_16x16x32_bf16(al[rt], b1, acc[rt][1], 0, 0, 0);
                }
            }
        }
    }

    // ---- epilogue: bias + relu + bf16, route by wt column ----
    #pragma unroll
    for (int rt = 0; rt < 4; ++rt) {
        #pragma unroll
        for (int c = 0; c < 2; ++c) {
            const int wtc  = cbase + w * 32 + c * 16 + l16;   // 0..639
            const int rowl = rt * 16 + quad * 4;
            const float bias = fg ? (wtc < 64 ? bf[wtc] : bg[wtc - 64]) : bh[wtc - 128];
            const floatx4 v = acc[rt][c];
            if (fg) {
                unsigned short* dst = (wtc < 64) ? (f_bf + wtc) : (g_bf + wtc - 64);
                #pragma unroll
                for (int r = 0; r < 4; ++r) {
                    const float z = v[r] + bias;
                    dst[(size_t)(R0 + rowl + r) * C_DIM] = f2bf(z > 0.f ? z : 0.f);
                }
            } else {
                const int hc   = wtc - 128;                   // global F col
                const int grow = R0 + rowl;
                const int b    = grow >> 12, rl = grow & 4095;
                const int T    = rl >> 6, mloc = rl & 63;
                const int kh2  = mloc >> 5, q2 = (mloc >> 3) & 3, j0 = mloc & 7;
                ushortx4 st;
                #pragma unroll
                for (int r = 0; r < 4; ++r) {
                    const float z = v[r] + bias;
                    st[r] = f2bf(z > 0.f ? z : 0.f);
                }
                const size_t off = ((((size_t)(b * 64 + T) * 64) + (hc >> 4) * 2 + kh2) * 64
                                    + q2 * 16 + (hc & 15)) * 8 + j0;
                *(ushortx4*)(h_sw + off) = st;
            }
        }
    }
}

// ---------------------------------------------------------------------------
// Kernel 2: MFMA attention, fully fused, COLUMN-SPLIT (round-3 post-mortem:
// attn time tracks per-CU h L2 traffic; halving QT doubled it and regressed
// 92->114 us. So maximize QT and split F-columns instead of keys).
//
// QT=128, KT=64, 1024 threads (16 waves), grid = 4 b x 32 q-tiles x 2
// column-halves = 256 blocks (1/CU). Each block sees ALL 4096 keys ->
// complete softmax denominator in-block (fused epilogue, no merge pass),
// but computes PV only for its 256 of 512 F-cols. Score work duplicated x2
// (+11% MFMA; QK is 11% of FLOPs) in exchange for h traffic 2 GB -> 0.5 GB.
//
// Score partition (as round 0): wave w -> rows (w&7)*16, cols (w>>3)*32 of
// the 128x64 score tile. PV partition: wave w owns ALL 128 rows x 16 F-cols
// (ch*256 + w*16); its 2 h frags are one contiguous 2 KB block -> 16 waves
// tile the 32 KB h half-tile exactly once per iter.
//
// LDS: exact 128 B stride + T2 XOR-swizzle (byte ^= (row&7)<<4), the
// verified-0-conflict pattern. Barriers lgkm-only (h/g global loads stay
// in flight). XCD map: XCD = b*2+ch -> each XCD streams one 2 MB h-half.
// ---------------------------------------------------------------------------
#define QT 128
#define KT 64

__global__ __launch_bounds__(1024, 4) void attn_mfma_kernel(
    const unsigned short* __restrict__ f_bf, const unsigned short* __restrict__ g_bf,
    const unsigned short* __restrict__ h_sw, const float* __restrict__ gamma,
    const float* __restrict__ V, float* __restrict__ out)
{
    __shared__ __align__(16) unsigned short p_lds[2][QT * 64];   // 32 KB, swizzled
    __shared__ __align__(16) unsigned short g_lds[2][KT * 64];   // 16 KB, swizzled
    __shared__ float l_red[2][QT];
    __shared__ float l_inv[QT];

    const int t = threadIdx.x;
    const int w = t >> 6, lane = t & 63, quad = lane >> 4, l16 = lane & 15;
    const int sr = (w & 7) * 16, sc = (w >> 3) * 32;   // score stripe

    // bid&7 = XCD = b*2 + ch; bid>>3 = q-tile. Each XCD's 32 blocks share
    // one batch's g (512 KB) and one 2 MB h column-half -> L2-resident.
    const int bid = blockIdx.x;
    const int b   = (bid & 7) >> 1;
    const int ch  = bid & 1;
    const int qb  = bid >> 3;
    const int R0  = qb * QT;

    const unsigned short* fb    = f_bf + ((size_t)b * 4096 + R0) * C_DIM;
    const unsigned short* gb    = g_bf + (size_t)b * 4096 * C_DIM;
    const unsigned short* hbase = h_sw + (size_t)b * 64 * 32768;
    const int hgrp = (ch * 16 + w) * 2;   // wave's h group base (cols ch*256+w*16)

    bf16x8 f0, f1;
    {
        const unsigned short* fr = fb + (size_t)(sr + l16) * C_DIM + quad * 8;
        f0 = *(const bf16x8*)fr;
        f1 = *(const bf16x8*)(fr + 32);
    }
    const float gam = gamma[ch * 256 + w * 16 + l16];

    floatx4 acc[8];   // [row-tile]; wave's 16 cols
    #pragma unroll
    for (int rt = 0; rt < 8; ++rt)
        acc[rt] = (floatx4){0.f, 0.f, 0.f, 0.f};
    float run_l[4] = {0.f, 0.f, 0.f, 0.f};

    // cooperative g stage: thread t -> (row=t>>4, 8 B chunk), swizzled dest
    const int grow    = t >> 4, gk = (t & 15) * 4;           // shorts
    const int g_swoff = grow * 128 + ((gk * 2) ^ ((grow & 7) << 4));
    ushortx4 greg = *(const ushortx4*)(gb + (size_t)grow * C_DIM + gk);

    // loop-invariant swizzled score-read offsets (2 ct groups)
    const int sgrow0  = sc + l16;
    const int sgrow1  = sc + 16 + l16;
    const int sg0_off0 = sgrow0 * 128 + ((quad * 16)      ^ ((sgrow0 & 7) << 4));
    const int sg0_off1 = sgrow0 * 128 + ((quad * 16 + 64) ^ ((sgrow0 & 7) << 4));
    const int sg1_off0 = sgrow1 * 128 + ((quad * 16)      ^ ((sgrow1 & 7) << 4));
    const int sg1_off1 = sgrow1 * 128 + ((quad * 16 + 64) ^ ((sgrow1 & 7) << 4));

    for (int it = 0; it < 64; ++it) {
        const int buf = it & 1;
        const unsigned short* ht = hbase + (size_t)it * 32768 + (size_t)hgrp * 512;

        // ---- h prefetch: this wave's contiguous 2 KB (groups hgrp, hgrp+1) ----
        const bf16x8 h0 = *(const bf16x8*)(ht + (size_t)lane * 8);
        const bf16x8 h1 = *(const bf16x8*)(ht + 512 + (size_t)lane * 8);

        *(ushortx4*)((unsigned char*)&g_lds[buf][0] + g_swoff) = greg;
        if (it < 63)
            greg = *(const ushortx4*)(gb + (size_t)((it + 1) * KT + grow) * C_DIM + gk);
        lgkm_barrier();   // g[buf] visible

        const unsigned char* gB = (const unsigned char*)&g_lds[buf][0];
        unsigned char*       pB = (unsigned char*)&p_lds[buf][0];

        // ---- scores stripe: rows sr..sr+16, cols sc..sc+32 ----
        {
            const bf16x8 ga0 = *(const bf16x8*)(gB + sg0_off0);
            const bf16x8 ga1 = *(const bf16x8*)(gB + sg0_off1);
            floatx4 cc = (floatx4){0.f, 0.f, 0.f, 0.f};
            cc = __builtin_amdgcn_mfma_f32_16x16x32_bf16(f0, ga0, cc, 0, 0, 0);
            cc = __builtin_amdgcn_mfma_f32_16x16x32_bf16(f1, ga1, cc, 0, 0, 0);
            const bf16x8 gb0 = *(const bf16x8*)(gB + sg1_off0);
            const bf16x8 gb1 = *(const bf16x8*)(gB + sg1_off1);
            floatx4 cd = (floatx4){0.f, 0.f, 0.f, 0.f};
            cd = __builtin_amdgcn_mfma_f32_16x16x32_bf16(f0, gb0, cd, 0, 0, 0);
            cd = __builtin_amdgcn_mfma_f32_16x16x32_bf16(f1, gb1, cd, 0, 0, 0);
            #pragma unroll
            for (int r = 0; r < 4; ++r) {
                const int prow = sr + quad * 4 + r;
                const int swp  = (prow & 7) << 4;
                const float p0 = __expf(cc[r] - 32.f);
                const float p1 = __expf(cd[r] - 32.f);
                run_l[r] += p0 + p1;
                *(unsigned short*)(pB + prow * 128 + (((sc + l16) * 2)      ^ swp)) = f2bf(p0);
                *(unsigned short*)(pB + prow * 128 + (((sc + 16 + l16) * 2) ^ swp)) = f2bf(p1);
            }
        }
        lgkm_barrier();   // p[buf] visible

        // ---- PV: all 128 rows x this wave's 16 cols ----
        #pragma unroll
        for (int rt = 0; rt < 8; ++rt) {
            const int prow = rt * 16 + l16;
            const int sw   = (prow & 7) << 4;
            const bf16x8 pf0 = *(const bf16x8*)(pB + prow * 128 + ((quad * 16)      ^ sw));
            const bf16x8 pf1 = *(const bf16x8*)(pB + prow * 128 + ((quad * 16 + 64) ^ sw));
            acc[rt] = __builtin_amdgcn_mfma_f32_16x16x32_bf16(pf0, h0, acc[rt], 0, 0, 0);
            acc[rt] = __builtin_amdgcn_mfma_f32_16x16x32_bf16(pf1, h1, acc[rt], 0, 0, 0);
        }
    }

    // ---- full row-sum l: shfl over l16, then LDS-sum across the 2 sc ----
    #pragma unroll
    for (int r = 0; r < 4; ++r) {
        float v = run_l[r];
        v += __shfl_xor(v, 1, 64);
        v += __shfl_xor(v, 2, 64);
        v += __shfl_xor(v, 4, 64);
        v += __shfl_xor(v, 8, 64);
        if (l16 == 0) l_red[w >> 3][sr + quad * 4 + r] = v;
    }
    __syncthreads();
    if (t < QT)
        l_inv[t] = 1.f / (l_red[0][t] + l_red[1][t]);
    __syncthreads();

    // ---- fused epilogue: out = gamma * O/l + V (fp32, final) ----
    const float* Vb = V   + ((size_t)b * 4096 + R0) * F_DIM;
    float*       ob = out + ((size_t)b * 4096 + R0) * F_DIM;
    const int col = ch * 256 + w * 16 + l16;
    #pragma unroll
    for (int rt = 0; rt < 8; ++rt) {
        #pragma unroll
        for (int r = 0; r < 4; ++r) {
            const int row = rt * 16 + quad * 4 + r;
            ob[(size_t)row * F_DIM + col] =
                gam * acc[rt][r] * l_inv[row] + Vb[(size_t)row * F_DIM + col];
        }
    }
}

// ---------------------------------------------------------------------------
extern "C" void kernel_launch(void* const* d_in, const int* in_sizes, int n_in,
                              void* d_out, int out_size, void* d_ws, size_t ws_size,
                              hipStream_t stream) {
    const float* V     = (const float*)d_in[0];
    const float* Wf    = (const float*)d_in[1];
    const float* bf    = (const float*)d_in[2];
    const float* Wg    = (const float*)d_in[3];
    const float* bg    = (const float*)d_in[4];
    const float* Wh    = (const float*)d_in[5];
    const float* bh    = (const float*)d_in[6];
    const float* gamma = (const float*)d_in[7];
    float* out = (float*)d_out;

    // ws: f 2MB | g 2MB | h_sw 16MB | wt_hi 0.64 | wt_lo 0.64
    unsigned short* f_bf  = (unsigned short*)d_ws;
    unsigned short* g_bf  = f_bf + (size_t)M_ROWS * C_DIM;
    unsigned short* h_sw  = g_bf + (size_t)M_ROWS * C_DIM;
    unsigned short* wt_hi = h_sw + (size_t)4 * F_DIM * 4096;
    unsigned short* wt_lo = wt_hi + (size_t)640 * F_DIM;

    prep_w_kernel<<<640, 64, 0, stream>>>(Wf, Wg, Wh, wt_hi, wt_lo);
    embed_mfma_kernel<<<dim3(M_ROWS / BM, 5), 256, 0, stream>>>(
        V, wt_hi, wt_lo, bf, bg, bh, f_bf, g_bf, h_sw);
    attn_mfma_kernel<<<256, 1024, 0, stream>>>(f_bf, g_bf, h_sw, gamma, V, out);
}